// Round 3
// baseline (95.610 us; speedup 1.0000x reference)
//
#include <hip/hip_runtime.h>

#define TIMESTEPS 1000
#define NROWS 16384                 // 64 batch * 256 H rows
#define ROWS_PER_WAVE 4
#define WAVES_PER_BLOCK 4
#define NBLOCKS (NROWS / (ROWS_PER_WAVE * WAVES_PER_BLOCK))   // 1024
#define TOTAL_ELEMS 16384000.0      // 64 * 1 * 256 * 1000

// Wave-synchronous, generation-tagged bins: each 64-lane wave owns a private
// 2048-int LDS region (R bins [0..1023], T bins [1024..2047]) and processes
// ROWS_PER_WAVE rows with NO __syncthreads in the hot loop. Bin entries are
// (gen<<8)|w with gen = row+1: atomicMax makes newer rows win over stale
// entries, so bins never need re-zeroing between rows. Decode is
// w = max(v - (gen<<8), 0)  (stale/empty -> 0, matching reference zeros;
// col 0 also decodes to 0, same as reference's max(0, 0)).
__global__ __launch_bounds__(256) void holo_row_loss(
    const float* __restrict__ rec,
    const float* __restrict__ tgt,
    double* __restrict__ block_partials)
{
    __shared__ int bins[WAVES_PER_BLOCK][2048];   // 32 KiB
    __shared__ float wave_sums[WAVES_PER_BLOCK];

    const int tid  = threadIdx.x;
    const int wav  = tid >> 6;
    const int lane = tid & 63;
    const int gw   = blockIdx.x * WAVES_PER_BLOCK + wav;   // global wave id

    int* __restrict__ binw = &bins[wav][0];

    // one-time zero (gen 0): 8 x int4 per lane, stride-16B layout
    int4 z4; z4.x = 0; z4.y = 0; z4.z = 0; z4.w = 0;
    int4* zb = (int4*)binw;
#pragma unroll
    for (int j = 0; j < 8; ++j) zb[j * 64 + lane] = z4;

    // prefetch ALL row data into registers before any DS dependency,
    // so global latency hides under the zero phase + row-0 scatter.
    const float4* rec4 = (const float4*)rec;
    const float4* tgt4 = (const float4*)tgt;
    float4 xr[ROWS_PER_WAVE], xt[ROWS_PER_WAVE];
#pragma unroll
    for (int r = 0; r < ROWS_PER_WAVE; ++r) {
        const int row = gw * ROWS_PER_WAVE + r;
        xr[r] = rec4[row * 64 + lane];
        xt[r] = tgt4[row * 64 + lane];
    }
    __builtin_amdgcn_wave_barrier();

    float s = 0.0f;   // per-lane partial stays < 2^24 -> exact

#pragma unroll 1
    for (int r = 0; r < ROWS_PER_WAVE; ++r) {
        const int base = (r + 1) << 8;    // generation tag

        // scatter: q = (int(x*1000) - 1) mod 1000, x==0 dropped.
        // f32 mul + trunc matches jnp astype(int32); q in [-1, 998].
#pragma unroll
        for (int j = 0; j < 4; ++j) {
            const float vr = (&xr[r].x)[j];
            const float vt = (&xt[r].x)[j];
            const int   w  = lane * 4 + j;        // column index, <= 255
            int q = (int)(vr * 1000.0f) - 1;
            if (q < 0) q += TIMESTEPS;
            if (vr != 0.0f) atomicMax(&binw[q], base | w);
            q = (int)(vt * 1000.0f) - 1;
            if (q < 0) q += TIMESTEPS;
            if (vt != 0.0f) atomicMax(&binw[1024 + q], base | w);
        }
        __builtin_amdgcn_wave_barrier();

        // sum phase: 8 ds_read_b128/lane, decode via max(v-base, 0).
        // pad bins [1000..1023] are never written -> decode to 0 both sides.
        const int4* r4 = (const int4*)binw;
        const int4* t4 = (const int4*)(binw + 1024);
#pragma unroll
        for (int k = 0; k < 4; ++k) {
            const int4 a = r4[k * 64 + lane];
            const int4 b = t4[k * 64 + lane];
            const int wa0 = max(a.x - base, 0), wb0 = max(b.x - base, 0);
            const int wa1 = max(a.y - base, 0), wb1 = max(b.y - base, 0);
            const int wa2 = max(a.z - base, 0), wb2 = max(b.z - base, 0);
            const int wa3 = max(a.w - base, 0), wb3 = max(b.w - base, 0);
            const float d0 = (float)(wa0 - wb0);
            const float d1 = (float)(wa1 - wb1);
            const float d2 = (float)(wa2 - wb2);
            const float d3 = (float)(wa3 - wb3);
            s = fmaf(d0, d0, s);
            s = fmaf(d1, d1, s);
            s = fmaf(d2, d2, s);
            s = fmaf(d3, d3, s);
        }
        __builtin_amdgcn_wave_barrier();
    }

    // wave reduce, then one double per block
    for (int off = 32; off > 0; off >>= 1) s += __shfl_down(s, off, 64);
    if (lane == 0) wave_sums[wav] = s;
    __syncthreads();
    if (tid == 0) {
        double bsum = (double)wave_sums[0] + (double)wave_sums[1]
                    + (double)wave_sums[2] + (double)wave_sums[3];
        block_partials[blockIdx.x] = bsum;
    }
}

// Deterministic final reduction: 1024 doubles, 4 independent loads/thread.
__global__ __launch_bounds__(256) void reduce_partials(
    const double* __restrict__ block_partials,
    float* __restrict__ out)
{
    __shared__ double wave_sums[4];
    const int tid = threadIdx.x;
    double s = 0.0;
#pragma unroll
    for (int i = 0; i < NBLOCKS / 256; ++i)
        s += block_partials[i * 256 + tid];
    for (int off = 32; off > 0; off >>= 1) s += __shfl_down(s, off, 64);
    if ((tid & 63) == 0) wave_sums[tid >> 6] = s;
    __syncthreads();
    if (tid == 0) {
        double tot = wave_sums[0] + wave_sums[1] + wave_sums[2] + wave_sums[3];
        out[0] = (float)(tot / TOTAL_ELEMS);
    }
}

extern "C" void kernel_launch(void* const* d_in, const int* in_sizes, int n_in,
                              void* d_out, int out_size, void* d_ws, size_t ws_size,
                              hipStream_t stream)
{
    const float* rec = (const float*)d_in[0];
    const float* tgt = (const float*)d_in[1];
    float* out = (float*)d_out;
    double* block_partials = (double*)d_ws;    // NBLOCKS * 8 = 8 KiB

    holo_row_loss<<<NBLOCKS, 256, 0, stream>>>(rec, tgt, block_partials);
    reduce_partials<<<1, 256, 0, stream>>>(block_partials, out);
}

// Round 4
// 77.253 us; speedup vs baseline: 1.2376x; 1.2376x over previous
//
#include <hip/hip_runtime.h>

#define TIMESTEPS 1000
#define NROWS 16384                 // 64 batch * 256 H rows
#define ROWS_PER_WAVE 4
#define WAVES_PER_BLOCK 4
#define NBLOCKS (NROWS / (ROWS_PER_WAVE * WAVES_PER_BLOCK))   // 1024
#define TOTAL_ELEMS 16384000.0      // 64 * 1 * 256 * 1000

// Wave-synchronous, generation-tagged bins: each 64-lane wave owns a private
// 2048-int LDS region (R bins [0..1023], T bins [1024..2047]) and processes
// ROWS_PER_WAVE rows with NO __syncthreads in the hot loop. Bin entries are
// (gen<<8)|w with gen = row+1: atomicMax makes newer rows win over stale
// entries, so bins never need re-zeroing between rows. Decode:
// w = max(v - (gen<<8), 0)  (stale/empty -> 0, matching reference zeros;
// col 0 also decodes to 0, same as reference's max(0, 0)).
//
// NOTE: the row loop MUST be fully unrolled — xr[]/xt[] are register arrays;
// a non-unrolled loop forces a scratch spill (R3 post-mortem: +20 us).
__global__ __launch_bounds__(256) void holo_row_loss(
    const float* __restrict__ rec,
    const float* __restrict__ tgt,
    double* __restrict__ block_partials)
{
    __shared__ int bins[WAVES_PER_BLOCK][2048];   // 32 KiB
    __shared__ float wave_sums[WAVES_PER_BLOCK];

    const int tid  = threadIdx.x;
    const int wav  = tid >> 6;
    const int lane = tid & 63;
    const int gw   = blockIdx.x * WAVES_PER_BLOCK + wav;   // global wave id

    int* __restrict__ binw = &bins[wav][0];

    // one-time zero (gen 0): 8 x int4 per lane, stride-16B layout
    int4 z4; z4.x = 0; z4.y = 0; z4.z = 0; z4.w = 0;
    int4* zb = (int4*)binw;
#pragma unroll
    for (int j = 0; j < 8; ++j) zb[j * 64 + lane] = z4;

    // prefetch ALL row data into registers (static indices only!) so global
    // latency hides under the zero phase + row-0 scatter.
    const float4* rec4 = (const float4*)rec;
    const float4* tgt4 = (const float4*)tgt;
    float4 xr[ROWS_PER_WAVE], xt[ROWS_PER_WAVE];
#pragma unroll
    for (int r = 0; r < ROWS_PER_WAVE; ++r) {
        const int row = gw * ROWS_PER_WAVE + r;
        xr[r] = rec4[row * 64 + lane];
        xt[r] = tgt4[row * 64 + lane];
    }
    __builtin_amdgcn_wave_barrier();

    float s = 0.0f;   // per-lane partial stays < 2^24 -> exact

#pragma unroll       // FULL unroll: keeps xr[r]/xt[r] in registers
    for (int r = 0; r < ROWS_PER_WAVE; ++r) {
        const int base = (r + 1) << 8;    // generation tag

        // scatter: q = (int(x*1000) - 1) mod 1000, x==0 dropped.
        // f32 mul + trunc matches jnp astype(int32); q in [-1, 998].
#pragma unroll
        for (int j = 0; j < 4; ++j) {
            const float vr = (&xr[r].x)[j];
            const float vt = (&xt[r].x)[j];
            const int   w  = lane * 4 + j;        // column index, <= 255
            int q = (int)(vr * 1000.0f) - 1;
            if (q < 0) q += TIMESTEPS;
            if (vr != 0.0f) atomicMax(&binw[q], base | w);
            q = (int)(vt * 1000.0f) - 1;
            if (q < 0) q += TIMESTEPS;
            if (vt != 0.0f) atomicMax(&binw[1024 + q], base | w);
        }
        __builtin_amdgcn_wave_barrier();

        // sum phase: 8 ds_read_b128/lane, decode via max(v-base, 0).
        // pad bins [1000..1023] are never written -> decode to 0 both sides.
        const int4* r4 = (const int4*)binw;
        const int4* t4 = (const int4*)(binw + 1024);
#pragma unroll
        for (int k = 0; k < 4; ++k) {
            const int4 a = r4[k * 64 + lane];
            const int4 b = t4[k * 64 + lane];
            const int wa0 = max(a.x - base, 0), wb0 = max(b.x - base, 0);
            const int wa1 = max(a.y - base, 0), wb1 = max(b.y - base, 0);
            const int wa2 = max(a.z - base, 0), wb2 = max(b.z - base, 0);
            const int wa3 = max(a.w - base, 0), wb3 = max(b.w - base, 0);
            const float d0 = (float)(wa0 - wb0);
            const float d1 = (float)(wa1 - wb1);
            const float d2 = (float)(wa2 - wb2);
            const float d3 = (float)(wa3 - wb3);
            s = fmaf(d0, d0, s);
            s = fmaf(d1, d1, s);
            s = fmaf(d2, d2, s);
            s = fmaf(d3, d3, s);
        }
        __builtin_amdgcn_wave_barrier();
    }

    // wave reduce, then one double per block
    for (int off = 32; off > 0; off >>= 1) s += __shfl_down(s, off, 64);
    if (lane == 0) wave_sums[wav] = s;
    __syncthreads();
    if (tid == 0) {
        double bsum = (double)wave_sums[0] + (double)wave_sums[1]
                    + (double)wave_sums[2] + (double)wave_sums[3];
        block_partials[blockIdx.x] = bsum;
    }
}

// Deterministic final reduction: 1024 doubles, 4 independent loads/thread.
__global__ __launch_bounds__(256) void reduce_partials(
    const double* __restrict__ block_partials,
    float* __restrict__ out)
{
    __shared__ double wave_sums[4];
    const int tid = threadIdx.x;
    double s = 0.0;
#pragma unroll
    for (int i = 0; i < NBLOCKS / 256; ++i)
        s += block_partials[i * 256 + tid];
    for (int off = 32; off > 0; off >>= 1) s += __shfl_down(s, off, 64);
    if ((tid & 63) == 0) wave_sums[tid >> 6] = s;
    __syncthreads();
    if (tid == 0) {
        double tot = wave_sums[0] + wave_sums[1] + wave_sums[2] + wave_sums[3];
        out[0] = (float)(tot / TOTAL_ELEMS);
    }
}

extern "C" void kernel_launch(void* const* d_in, const int* in_sizes, int n_in,
                              void* d_out, int out_size, void* d_ws, size_t ws_size,
                              hipStream_t stream)
{
    const float* rec = (const float*)d_in[0];
    const float* tgt = (const float*)d_in[1];
    float* out = (float*)d_out;
    double* block_partials = (double*)d_ws;    // NBLOCKS * 8 = 8 KiB

    holo_row_loss<<<NBLOCKS, 256, 0, stream>>>(rec, tgt, block_partials);
    reduce_partials<<<1, 256, 0, stream>>>(block_partials, out);
}